// Round 12
// baseline (994.625 us; speedup 1.0000x reference)
//
#include <hip/hip_runtime.h>
#include <stdint.h>

// TernBinLayer: out = binarise(x @ W), x in {-1,+1}, W in {-1,0,+1}.
// Round 12 = round 10/11 with the nontemporal-store type fixed:
// __builtin_nontemporal_store rejects HIP's uint4 class; use a native
// clang ext_vector_type(4) instead (same global_store_dwordx4 nt).
// Two-phase LDS-signs structure with:
//  (i) stage phase: 4 NAMED uint4 loads + one sched_barrier(0) after the
//      load group (round 9's VGPR=20 showed loads were serialized);
//  (ii) compute phase: 4 rows/pass + quad 4x4 transpose via 3 __shfl_xor
//      -> 16B/lane nontemporal stores (store instructions /4).

#define NROWS  524288
#define DDIM   256
#define BLOCKS 2048
#define RPB    (NROWS / BLOCKS)   // 256 rows per block
#define RPW    (RPB / 4)          // 64 rows staged per wave

typedef uint32_t u32;
typedef unsigned long long u64;
typedef unsigned int u32x4 __attribute__((ext_vector_type(4)));

// Ballot one row (held in uint4 xv) into 8 sign words and write words
// 0..7 from lanes 0..7 of the wave. Layout: element k of a row ->
// word ((k&3)<<1)|(k>>7), bit (k>>2)&31.
#define BALLOT_STAGE(xv, ridx)                                            \
    {                                                                     \
        const u64 _q0 = __ballot((int)(xv).x < 0);                        \
        const u64 _q1 = __ballot((int)(xv).y < 0);                        \
        const u64 _q2 = __ballot((int)(xv).z < 0);                        \
        const u64 _q3 = __ballot((int)(xv).w < 0);                        \
        const u32 _w0 = (u32)_q0, _w1 = (u32)(_q0 >> 32);                 \
        const u32 _w2 = (u32)_q1, _w3 = (u32)(_q1 >> 32);                 \
        const u32 _w4 = (u32)_q2, _w5 = (u32)(_q2 >> 32);                 \
        const u32 _w6 = (u32)_q3, _w7 = (u32)(_q3 >> 32);                 \
        const u32 _sel = wb2 ? (wb1 ? (wb0 ? _w7 : _w6)                   \
                                    : (wb0 ? _w5 : _w4))                  \
                             : (wb1 ? (wb0 ? _w3 : _w2)                   \
                                    : (wb0 ? _w1 : _w0));                 \
        if (writer) signs[(ridx)][lane] = _sel;                           \
    }

// dot for one row r against this lane's column masks -> +-1.0f bits
#define DOTROW(dst, r)                                                    \
    {                                                                     \
        const uint4 _sa = *reinterpret_cast<const uint4*>(&signs[(r)][0]);\
        const uint4 _sb = *reinterpret_cast<const uint4*>(&signs[(r)][4]);\
        int _p = 0;                                                       \
        _p += __popc((_sa.x ^ M0) & A0);                                  \
        _p += __popc((_sa.y ^ M1) & A1);                                  \
        _p += __popc((_sa.z ^ M2) & A2);                                  \
        _p += __popc((_sa.w ^ M3) & A3);                                  \
        _p += __popc((_sb.x ^ M4) & A4);                                  \
        _p += __popc((_sb.y ^ M5) & A5);                                  \
        _p += __popc((_sb.z ^ M6) & A6);                                  \
        _p += __popc((_sb.w ^ M7) & A7);                                  \
        const int _d = C - 2 * _p;                                        \
        (dst) = 0x3f800000u | ((u32)_d & 0x80000000u);                    \
    }

// select among o0..o3 by runtime 2-bit index j (named scalars -> cndmask,
// no scratch per rule #20)
#define PICK(j) (((j) & 2) ? (((j) & 1) ? o3 : o2) : (((j) & 1) ? o1 : o0))
// select among own/rr1/rr2/rr3 by runtime distance d
#define SEL(d) ((d) == 0 ? own : ((d) == 1 ? rr1 : ((d) == 2 ? rr2 : rr3)))

__global__ __launch_bounds__(256, 4)
void ternbin_kernel(const float* __restrict__ x, const float* __restrict__ W,
                    float* __restrict__ out) {
    __shared__ u32 signs[RPB][8];   // 8 KB: sign words for the block's rows

    const int t    = threadIdx.x;   // 0..255
    const int lane = t & 63;
    const int wv   = t >> 6;
    const int col  = (wv << 6) | lane;

    // ---- Masks for THIS lane's column (16 VGPRs) ----
    u32 A0=0,A1=0,A2=0,A3=0,A4=0,A5=0,A6=0,A7=0;
    u32 M0=0,M1=0,M2=0,M3=0,M4=0,M5=0,M6=0,M7=0;
    #pragma unroll 8
    for (int k = 0; k < DDIM; ++k) {
        const float v = W[k * DDIM + col];
        const int   w = ((k & 3) << 1) | (k >> 7);
        const u32 bit = 1u << ((k >> 2) & 31);
        const u32 nz  = (v != 0.0f) ? bit : 0u;
        const u32 ng  = (v <  0.0f) ? bit : 0u;
        switch (w) {
            case 0: A0 |= nz; M0 |= ng; break;
            case 1: A1 |= nz; M1 |= ng; break;
            case 2: A2 |= nz; M2 |= ng; break;
            case 3: A3 |= nz; M3 |= ng; break;
            case 4: A4 |= nz; M4 |= ng; break;
            case 5: A5 |= nz; M5 |= ng; break;
            case 6: A6 |= nz; M6 |= ng; break;
            case 7: A7 |= nz; M7 |= ng; break;
        }
    }
    const int C = __popc(A0) + __popc(A1) + __popc(A2) + __popc(A3)
                + __popc(A4) + __popc(A5) + __popc(A6) + __popc(A7);

    const size_t row0 = (size_t)blockIdx.x * RPB;

    // ---- Stage phase: wave wv ballots rows [wv*64, wv*64+64) into LDS ----
    {
        const float* xp = x + (row0 + (size_t)wv * RPW) * DDIM + 4 * lane;
        const bool writer = (lane < 8);
        const bool wb2 = (lane & 4) != 0;
        const bool wb1 = (lane & 2) != 0;
        const bool wb0 = (lane & 1) != 0;

        #pragma unroll 1
        for (int r = 0; r < RPW; r += 4) {
            // 4 named loads; single fence keeps them concurrently in flight
            uint4 v0 = *reinterpret_cast<const uint4*>(xp + (size_t)(r + 0) * DDIM);
            uint4 v1 = *reinterpret_cast<const uint4*>(xp + (size_t)(r + 1) * DDIM);
            uint4 v2 = *reinterpret_cast<const uint4*>(xp + (size_t)(r + 2) * DDIM);
            uint4 v3 = *reinterpret_cast<const uint4*>(xp + (size_t)(r + 3) * DDIM);
            __builtin_amdgcn_sched_barrier(0);
            const int rb = wv * RPW + r;
            BALLOT_STAGE(v0, rb + 0);
            BALLOT_STAGE(v1, rb + 1);
            BALLOT_STAGE(v2, rb + 2);
            BALLOT_STAGE(v3, rb + 3);
        }
    }
    __syncthreads();

    // ---- Compute phase: 4 rows/pass, quad-transpose, 16B nt stores ----
    const int s  = lane & 3;          // row-within-group this lane stores
    const int q4 = lane & ~3;         // column base (4*quad) within wave
    float* oq = out + row0 * DDIM + (wv << 6) + q4;

    #pragma unroll 2
    for (int rp = 0; rp < RPB; rp += 4) {
        u32 o0, o1, o2, o3;           // results: row rp+k, this lane's col
        DOTROW(o0, rp + 0);
        DOTROW(o1, rp + 1);
        DOTROW(o2, rp + 2);
        DOTROW(o3, rp + 3);

        // 4x4 transpose within each quad: after this, lane (q,s) holds
        // row rp+s, cols 4q..4q+3. Each lane sends PICK(s^m) at xor-dist m;
        // receives SEL(d) with d = s^k placed at component k.
        const u32 own = PICK(s);
        const u32 rr1 = __shfl_xor(PICK(s ^ 1), 1);
        const u32 rr2 = __shfl_xor(PICK(s ^ 2), 2);
        const u32 rr3 = __shfl_xor(PICK(s ^ 3), 3);
        u32x4 ov;
        ov.x = SEL(s);
        ov.y = SEL(s ^ 1);
        ov.z = SEL(s ^ 2);
        ov.w = SEL(s ^ 3);

        __builtin_nontemporal_store(ov,
            reinterpret_cast<u32x4*>(oq + (size_t)(rp + s) * DDIM));
    }
}

extern "C" void kernel_launch(void* const* d_in, const int* in_sizes, int n_in,
                              void* d_out, int out_size, void* d_ws, size_t ws_size,
                              hipStream_t stream) {
    const float* x = (const float*)d_in[0];
    const float* W = (const float*)d_in[1];
    float* out = (float*)d_out;
    // 2048 blocks x 4 waves; block b owns rows [b*256, (b+1)*256).
    ternbin_kernel<<<BLOCKS, 256, 0, stream>>>(x, W, out);
}